// Round 5
// baseline (415.775 us; speedup 1.0000x reference)
//
#include <hip/hip_runtime.h>

typedef unsigned short u16;
typedef short short8 __attribute__((ext_vector_type(8)));
typedef float floatx4 __attribute__((ext_vector_type(4)));

#define NE 800000
#define NNODES 50000

#define LDS_FENCE() __asm__ volatile("s_waitcnt lgkmcnt(0)" ::: "memory")

__device__ __forceinline__ u16 f2bf(float f) {
    union { float f; unsigned int i; } v; v.f = f;
    return (u16)((v.i + 0x7fffu + ((v.i >> 16) & 1u)) >> 16);
}
__device__ __forceinline__ float bf2f(u16 u) {
    union { unsigned int i; float f; } v; v.i = ((unsigned int)u) << 16; return v.f;
}
// load 8 consecutive fp32, round to bf16, return packed short8
__device__ __forceinline__ short8 ld8_bf(const float* __restrict__ p) {
    const float4 a = *(const float4*)p;
    const float4 b = *(const float4*)(p + 4);
    short8 o;
    o[0] = (short)f2bf(a.x); o[1] = (short)f2bf(a.y);
    o[2] = (short)f2bf(a.z); o[3] = (short)f2bf(a.w);
    o[4] = (short)f2bf(b.x); o[5] = (short)f2bf(b.y);
    o[6] = (short)f2bf(b.z); o[7] = (short)f2bf(b.w);
    return o;
}

#define MFMA16(a, b, c) __builtin_amdgcn_mfma_f32_16x16x32_bf16(a, b, c, 0, 0, 0)

// ---------------------------------------------------------------------------
// Counting sort of edges by dst: hist -> exclusive scan -> scatter perm
// ---------------------------------------------------------------------------
__global__ __launch_bounds__(256) void hist_kernel(
    const int* __restrict__ ei, int* __restrict__ hist)
{
    const int e = blockIdx.x * 256 + threadIdx.x;
    if (e < NE) atomicAdd(&hist[ei[NE + e]], 1);
}

__global__ __launch_bounds__(1024) void scan_kernel(
    const int* __restrict__ hist, int* __restrict__ offs, int* __restrict__ cursor)
{
    __shared__ int buf[1024];
    __shared__ int carry;
    const int tid = threadIdx.x;
    if (tid == 0) carry = 0;
    __syncthreads();
    for (int base = 0; base < NNODES; base += 1024) {
        const int i = base + tid;
        const int v = (i < NNODES) ? hist[i] : 0;
        buf[tid] = v;
        __syncthreads();
        #pragma unroll
        for (int off = 1; off < 1024; off <<= 1) {
            const int t = (tid >= off) ? buf[tid - off] : 0;
            __syncthreads();
            buf[tid] += t;
            __syncthreads();
        }
        const int excl = buf[tid] - v + carry;   // exclusive prefix + carry
        if (i < NNODES) { offs[i] = excl; cursor[i] = excl; }
        __syncthreads();
        if (tid == 0) carry += buf[1023];
        __syncthreads();
    }
}

__global__ __launch_bounds__(256) void scatter_kernel(
    const int* __restrict__ ei, int* __restrict__ cursor, int* __restrict__ perm)
{
    const int e = blockIdx.x * 256 + threadIdx.x;
    if (e < NE) {
        const int p = atomicAdd(&cursor[ei[NE + e]], 1);
        perm[p] = e;
    }
}

// ---------------------------------------------------------------------------
// Edge kernel: per 16-edge tile (one wave), edges in dst-sorted order (perm):
//   A1[16x96] = [bf16(x[src]) | bf16(edge_feat) | zero pad]
//   h   = relu(A1 @ W1 + b1)   (MFMA K=96, W1 zero-padded k>=80)
//   msg = h @ W2 + b2          (h via LDS C->A layout round trip)
//   segmented per-wave reduction over sorted dst -> ~2 atomics/lane/tile
// ---------------------------------------------------------------------------
__global__ __launch_bounds__(256) void edge_kernel(
    const float* __restrict__ x, const int* __restrict__ ei,
    const float* __restrict__ ef, const float* __restrict__ w1,
    const float* __restrict__ b1, const float* __restrict__ w2,
    const float* __restrict__ b2, const int* __restrict__ perm,
    float* __restrict__ agg)
{
    constexpr int S1 = 104;  // A1 row stride (bf16): pad 96->104 (2-way alias only)
    constexpr int S2 = 72;   // h row stride: pad 64->72
    __shared__ u16 A1[4][16 * S1];
    __shared__ u16 Hs[4][16 * S2];
    __shared__ float Ms[4][16 * 64];
    __shared__ int Ds[4][16];

    const int wid  = threadIdx.x >> 6;
    const int lane = threadIdx.x & 63;
    const int q    = lane >> 4;   // quad (16-lane group)
    const int c    = lane & 15;   // col within quad

    // B-fragments, register resident. B[k][n]: n = 16*nn + c, k = 32*kk + q*8 + j
    short8 w1f[3][4], w2f[2][4];
    #pragma unroll
    for (int kk = 0; kk < 3; ++kk)
        #pragma unroll
        for (int nn = 0; nn < 4; ++nn)
            #pragma unroll
            for (int j = 0; j < 8; ++j) {
                const int k = kk * 32 + q * 8 + j;
                w1f[kk][nn][j] = (k < 80) ? (short)f2bf(w1[k * 64 + nn * 16 + c]) : (short)0;
            }
    #pragma unroll
    for (int kk = 0; kk < 2; ++kk)
        #pragma unroll
        for (int nn = 0; nn < 4; ++nn)
            #pragma unroll
            for (int j = 0; j < 8; ++j) {
                const int k = kk * 32 + q * 8 + j;
                w2f[kk][nn][j] = (short)f2bf(w2[k * 64 + nn * 16 + c]);
            }
    float b1v[4], b2v[4];
    #pragma unroll
    for (int nn = 0; nn < 4; ++nn) {
        b1v[nn] = b1[nn * 16 + c];
        b2v[nn] = b2[nn * 16 + c];
    }

    // zero pad region (cols 80..96) once — never overwritten
    if (q == 1) {
        const short8 z8 = {0, 0, 0, 0, 0, 0, 0, 0};
        *(short8*)&A1[wid][c * S1 + 80] = z8;
        *(short8*)&A1[wid][c * S1 + 88] = z8;
    }

    const floatx4 zero = {0.f, 0.f, 0.f, 0.f};
    const int ntile = NE / 16;  // 50000 exactly

    for (int t = blockIdx.x * 4 + wid; t < ntile; t += gridDim.x * 4) {
        const int e0 = t * 16;
        const int m = c;                    // row this lane stages
        const int e = perm[e0 + m];         // dst-sorted edge id
        u16* arow = &A1[wid][m * S1];

        const int src = ei[e];
        const float* xp = x + (size_t)src * 64 + q * 16;
        *(short8*)&arow[q * 16]     = ld8_bf(xp);
        *(short8*)&arow[q * 16 + 8] = ld8_bf(xp + 8);
        if (q == 0) {
            const float* ep = ef + (size_t)e * 16;
            *(short8*)&arow[64] = ld8_bf(ep);
            *(short8*)&arow[72] = ld8_bf(ep + 8);
        } else if (q == 2) {
            Ds[wid][m] = ei[NE + e];
        }
        LDS_FENCE();

        // A fragments: A[m = c][k = 32*kk + q*8 + j]  (wave-private LDS)
        short8 a1k[3];
        #pragma unroll
        for (int kk = 0; kk < 3; ++kk)
            a1k[kk] = *(const short8*)&A1[wid][c * S1 + kk * 32 + q * 8];

        // GEMM1 + bias + relu -> Hs (bf16, row-major => A-layout-ready)
        #pragma unroll
        for (int nn = 0; nn < 4; ++nn) {
            floatx4 acc = MFMA16(a1k[0], w1f[0][nn], zero);
            acc = MFMA16(a1k[1], w1f[1][nn], acc);
            acc = MFMA16(a1k[2], w1f[2][nn], acc);
            #pragma unroll
            for (int r = 0; r < 4; ++r) {
                const float h = fmaxf(acc[r] + b1v[nn], 0.f);
                Hs[wid][(q * 4 + r) * S2 + nn * 16 + c] = f2bf(h);
            }
        }
        LDS_FENCE();

        short8 a2k[2];
        #pragma unroll
        for (int kk = 0; kk < 2; ++kk)
            a2k[kk] = *(const short8*)&Hs[wid][c * S2 + kk * 32 + q * 8];

        // GEMM2 -> fp32 msg tile in LDS (row-major [16][64])
        #pragma unroll
        for (int nn = 0; nn < 4; ++nn) {
            floatx4 mg = MFMA16(a2k[0], w2f[0][nn], zero);
            mg = MFMA16(a2k[1], w2f[1][nn], mg);
            #pragma unroll
            for (int r = 0; r < 4; ++r)
                Ms[wid][(q * 4 + r) * 64 + nn * 16 + c] = mg[r] + b2v[nn];
        }
        LDS_FENCE();

        // segmented reduction over sorted dst (wave-uniform branches):
        // lane = column; runs of equal Ds combined before one atomic per run
        int dcur = Ds[wid][0];
        float acc = Ms[wid][lane];
        #pragma unroll
        for (int row = 1; row < 16; ++row) {
            const int d = Ds[wid][row];
            const float v = Ms[wid][row * 64 + lane];
            if (d == dcur) {
                acc += v;
            } else {
                atomicAdd(&agg[(size_t)dcur * 64 + lane], acc);
                dcur = d;
                acc = v;
            }
        }
        atomicAdd(&agg[(size_t)dcur * 64 + lane], acc);
    }
}

// ---------------------------------------------------------------------------
// Node kernel: per 16-node tile (one wave):
//   cat[16x128] = [bf16(x) | bf16(agg/(cnt+1e-8))], cnt = hist (int)
//   upd = relu(cat @ W3 + b3); y = upd + x; LayerNorm(y)*gamma+beta -> fp32 out
// ---------------------------------------------------------------------------
__global__ __launch_bounds__(256) void node_kernel(
    const float* __restrict__ x, const float* __restrict__ w3,
    const float* __restrict__ b3, const float* __restrict__ g,
    const float* __restrict__ bb, const float* __restrict__ agg,
    const int* __restrict__ hist, float* __restrict__ out)
{
    constexpr int S3 = 136;  // 128 + 8 pad
    __shared__ u16 Cs[4][16 * S3];

    const int wid  = threadIdx.x >> 6;
    const int lane = threadIdx.x & 63;
    const int q    = lane >> 4;
    const int c    = lane & 15;

    short8 w3f[4][4];
    #pragma unroll
    for (int kk = 0; kk < 4; ++kk)
        #pragma unroll
        for (int nn = 0; nn < 4; ++nn)
            #pragma unroll
            for (int j = 0; j < 8; ++j) {
                const int k = kk * 32 + q * 8 + j;
                w3f[kk][nn][j] = (short)f2bf(w3[k * 64 + nn * 16 + c]);
            }
    float b3v[4], gv[4], bv[4];
    #pragma unroll
    for (int nn = 0; nn < 4; ++nn) {
        b3v[nn] = b3[nn * 16 + c];
        gv[nn]  = g[nn * 16 + c];
        bv[nn]  = bb[nn * 16 + c];
    }

    const floatx4 zero = {0.f, 0.f, 0.f, 0.f};
    const int ntile = NNODES / 16;  // 3125 exactly

    for (int t = blockIdx.x * 4 + wid; t < ntile; t += gridDim.x * 4) {
        const int n0 = t * 16;
        const int m = c;
        const int node = n0 + m;
        u16* crow = &Cs[wid][m * S3];

        if (q < 2) {
            const float* xp = x + (size_t)node * 64 + q * 32;
            #pragma unroll
            for (int gi = 0; gi < 4; ++gi)
                *(short8*)&crow[q * 32 + gi * 8] = ld8_bf(xp + gi * 8);
        } else {
            const int p = q - 2;
            const float inv = 1.0f / ((float)hist[node] + 1e-8f);
            const float* ap = agg + (size_t)node * 64 + p * 32;
            #pragma unroll
            for (int gi = 0; gi < 4; ++gi) {
                const float4 v0 = *(const float4*)(ap + gi * 8);
                const float4 v1 = *(const float4*)(ap + gi * 8 + 4);
                short8 o;
                o[0] = (short)f2bf(v0.x * inv);
                o[1] = (short)f2bf(v0.y * inv);
                o[2] = (short)f2bf(v0.z * inv);
                o[3] = (short)f2bf(v0.w * inv);
                o[4] = (short)f2bf(v1.x * inv);
                o[5] = (short)f2bf(v1.y * inv);
                o[6] = (short)f2bf(v1.z * inv);
                o[7] = (short)f2bf(v1.w * inv);
                *(short8*)&crow[64 + p * 32 + gi * 8] = o;
            }
        }
        LDS_FENCE();

        short8 af[4];
        #pragma unroll
        for (int kk = 0; kk < 4; ++kk)
            af[kk] = *(const short8*)&Cs[wid][c * S3 + kk * 32 + q * 8];

        float y[4][4];
        float s[4]  = {0.f, 0.f, 0.f, 0.f};
        float ss[4] = {0.f, 0.f, 0.f, 0.f};
        #pragma unroll
        for (int nn = 0; nn < 4; ++nn) {
            floatx4 acc = MFMA16(af[0], w3f[0][nn], zero);
            acc = MFMA16(af[1], w3f[1][nn], acc);
            acc = MFMA16(af[2], w3f[2][nn], acc);
            acc = MFMA16(af[3], w3f[3][nn], acc);
            #pragma unroll
            for (int r = 0; r < 4; ++r) {
                const float upd = fmaxf(acc[r] + b3v[nn], 0.f);
                const float xv = bf2f(Cs[wid][(q * 4 + r) * S3 + nn * 16 + c]);
                const float yy = upd + xv;
                y[r][nn] = yy;
                s[r] += yy;
                ss[r] += yy * yy;
            }
        }

        // LayerNorm per row: row q*4+r lives in this quad's 16 lanes x 4 regs
        #pragma unroll
        for (int r = 0; r < 4; ++r) {
            float sr = s[r], sq = ss[r];
            #pragma unroll
            for (int off = 1; off < 16; off <<= 1) {
                sr += __shfl_xor(sr, off);
                sq += __shfl_xor(sq, off);
            }
            const float mu  = sr * (1.0f / 64.0f);
            const float var = sq * (1.0f / 64.0f) - mu * mu;
            const float rs  = rsqrtf(var + 1e-5f);
            float* op = out + (size_t)(n0 + q * 4 + r) * 64 + c;
            #pragma unroll
            for (int nn = 0; nn < 4; ++nn)
                op[nn * 16] = (y[r][nn] - mu) * rs * gv[nn] + bv[nn];
        }
    }
}

extern "C" void kernel_launch(void* const* d_in, const int* in_sizes, int n_in,
                              void* d_out, int out_size, void* d_ws, size_t ws_size,
                              hipStream_t stream) {
    const float* x   = (const float*)d_in[0];
    const int*   ei  = (const int*)d_in[1];
    const float* ef  = (const float*)d_in[2];
    const float* w1  = (const float*)d_in[3];
    const float* b1  = (const float*)d_in[4];
    const float* w2  = (const float*)d_in[5];
    const float* b2  = (const float*)d_in[6];
    const float* w3  = (const float*)d_in[7];
    const float* b3  = (const float*)d_in[8];
    const float* g   = (const float*)d_in[9];
    const float* bb  = (const float*)d_in[10];

    // ws layout (4-byte units): agg[3.2M] | hist[50k] | offs[50k] | cursor[50k] | perm[800k]
    float* agg   = (float*)d_ws;
    int*  hist   = (int*)d_ws + 3200000;
    int*  offs   = hist + NNODES;
    int*  cursor = offs + NNODES;
    int*  perm   = cursor + NNODES;

    // zero agg + hist in one contiguous memset
    hipMemsetAsync(d_ws, 0, (size_t)(3200000 + NNODES) * sizeof(float), stream);
    hist_kernel<<<(NE + 255) / 256, 256, 0, stream>>>(ei, hist);
    scan_kernel<<<1, 1024, 0, stream>>>(hist, offs, cursor);
    scatter_kernel<<<(NE + 255) / 256, 256, 0, stream>>>(ei, cursor, perm);
    edge_kernel<<<1024, 256, 0, stream>>>(x, ei, ef, w1, b1, w2, b2, perm, agg);
    node_kernel<<<392, 256, 0, stream>>>(x, w3, b3, g, bb, agg, hist, (float*)d_out);
}

// Round 6
// 298.875 us; speedup vs baseline: 1.3911x; 1.3911x over previous
//
#include <hip/hip_runtime.h>

typedef unsigned short u16;
typedef short short8 __attribute__((ext_vector_type(8)));
typedef short short4v __attribute__((ext_vector_type(4)));
typedef float floatx4 __attribute__((ext_vector_type(4)));

#define NE 800000
#define NNODES 50000
#define NBLK 196  // ceil(50000/256)

#define LDS_FENCE() __asm__ volatile("s_waitcnt lgkmcnt(0)" ::: "memory")

__device__ __forceinline__ u16 f2bf(float f) {
    union { float f; unsigned int i; } v; v.f = f;
    return (u16)((v.i + 0x7fffu + ((v.i >> 16) & 1u)) >> 16);
}
__device__ __forceinline__ float bf2f(u16 u) {
    union { unsigned int i; float f; } v; v.i = ((unsigned int)u) << 16; return v.f;
}
__device__ __forceinline__ short8 pack8(const float4 a, const float4 b) {
    short8 o;
    o[0] = (short)f2bf(a.x); o[1] = (short)f2bf(a.y);
    o[2] = (short)f2bf(a.z); o[3] = (short)f2bf(a.w);
    o[4] = (short)f2bf(b.x); o[5] = (short)f2bf(b.y);
    o[6] = (short)f2bf(b.z); o[7] = (short)f2bf(b.w);
    return o;
}
__device__ __forceinline__ short8 ld8_bf(const float* __restrict__ p) {
    return pack8(*(const float4*)p, *(const float4*)(p + 4));
}

#define MFMA16(a, b, c) __builtin_amdgcn_mfma_f32_16x16x32_bf16(a, b, c, 0, 0, 0)

// ---------------------------------------------------------------------------
// Counting sort by dst: hist -> hierarchical exclusive scan -> scatter
// ---------------------------------------------------------------------------
__global__ __launch_bounds__(256) void hist_kernel(
    const int* __restrict__ ei, int* __restrict__ hist)
{
    const int e = blockIdx.x * 256 + threadIdx.x;
    if (e < NE) atomicAdd(&hist[ei[NE + e]], 1);
}

// per-block exclusive scan (shuffle-based), write local excl + block total
__global__ __launch_bounds__(256) void scan1_kernel(
    const int* __restrict__ hist, int* __restrict__ cursor, int* __restrict__ bsum)
{
    const int i = blockIdx.x * 256 + threadIdx.x;
    const int lane = threadIdx.x & 63;
    const int w = threadIdx.x >> 6;
    const int v = (i < NNODES) ? hist[i] : 0;
    int inc = v;
    #pragma unroll
    for (int o = 1; o < 64; o <<= 1) {
        const int tt = __shfl_up(inc, o);
        if (lane >= o) inc += tt;
    }
    __shared__ int ws[4];
    if (lane == 63) ws[w] = inc;
    __syncthreads();
    int add = 0;
    for (int j = 0; j < w; ++j) add += ws[j];
    const int excl = inc - v + add;
    if (i < NNODES) cursor[i] = excl;
    if (threadIdx.x == 255) bsum[blockIdx.x] = excl + v;
}

// scan the (<=256) block totals in one block
__global__ __launch_bounds__(256) void scan2_kernel(
    const int* __restrict__ bsum, int* __restrict__ bsumx)
{
    const int tid = threadIdx.x;
    const int lane = tid & 63;
    const int w = tid >> 6;
    const int v = (tid < NBLK) ? bsum[tid] : 0;
    int inc = v;
    #pragma unroll
    for (int o = 1; o < 64; o <<= 1) {
        const int tt = __shfl_up(inc, o);
        if (lane >= o) inc += tt;
    }
    __shared__ int ws[4];
    if (lane == 63) ws[w] = inc;
    __syncthreads();
    int add = 0;
    for (int j = 0; j < w; ++j) add += ws[j];
    bsumx[tid] = inc - v + add;
}

__global__ __launch_bounds__(256) void scan3_kernel(
    int* __restrict__ cursor, const int* __restrict__ bsumx)
{
    const int i = blockIdx.x * 256 + threadIdx.x;
    if (i < NNODES) cursor[i] += bsumx[blockIdx.x];
}

// scatter: materialize src, dst, edge-id in dst-sorted order
__global__ __launch_bounds__(256) void scatter_kernel(
    const int* __restrict__ ei, int* __restrict__ cursor,
    int* __restrict__ srcs, int* __restrict__ dsts, int* __restrict__ eidx)
{
    const int e = blockIdx.x * 256 + threadIdx.x;
    if (e < NE) {
        const int dst = ei[NE + e];
        const int p = atomicAdd(&cursor[dst], 1);
        srcs[p] = ei[e];
        dsts[p] = dst;
        eidx[p] = e;
    }
}

// ---------------------------------------------------------------------------
// Edge kernel, software-pipelined: per 16-edge tile (one wave), dst-sorted:
//   A1[16x96] = [bf16(x[src]) | bf16(edge_feat) | zero pad]
//   h   = relu(A1 @ W1 + b1)   (MFMA K=96, W1 zero-padded k>=80)
//   msg = h @ W2 + b2          (W2 frags from LDS; msg bf16 overlaid in Hs)
//   segmented per-wave reduction over sorted dst -> ~2 atomics/lane/tile
// Prefetch: indices depth-2, gathered data depth-1 (hidden under MFMA).
// ---------------------------------------------------------------------------
__global__ __launch_bounds__(256) void edge_kernel(
    const float* __restrict__ x, const float* __restrict__ ef,
    const float* __restrict__ w1, const float* __restrict__ b1,
    const float* __restrict__ w2, const float* __restrict__ b2,
    const int* __restrict__ srcs, const int* __restrict__ dsts,
    const int* __restrict__ eidx, float* __restrict__ agg)
{
    constexpr int S1 = 104;  // A1 row stride (bf16): pad 96->104
    constexpr int S2 = 72;   // h/msg row stride: pad 64->72
    __shared__ u16 A1[4][16 * S1];
    __shared__ u16 Hs[4][16 * S2];
    __shared__ int Ds[4][16];
    __shared__ u16 W2f[2][4][64 * 8];  // per-lane W2 B-frags (8 KB, block-shared)

    const int wid  = threadIdx.x >> 6;
    const int lane = threadIdx.x & 63;
    const int q    = lane >> 4;   // quad
    const int c    = lane & 15;   // col within quad
    const int r4   = lane >> 2;   // ef row handled by this lane
    const int p4   = lane & 3;    // ef float4 part

    // W1 B-frags in registers (48 VGPR). B[k][n]: n=16*nn+c, k=32*kk+q*8+j
    short8 w1f[3][4];
    #pragma unroll
    for (int kk = 0; kk < 3; ++kk)
        #pragma unroll
        for (int nn = 0; nn < 4; ++nn)
            #pragma unroll
            for (int j = 0; j < 8; ++j) {
                const int k = kk * 32 + q * 8 + j;
                w1f[kk][nn][j] = (k < 80) ? (short)f2bf(w1[k * 64 + nn * 16 + c]) : (short)0;
            }
    // W2 B-frags into LDS once (wave 0 computes, all read per tile)
    if (wid == 0) {
        #pragma unroll
        for (int kk = 0; kk < 2; ++kk)
            #pragma unroll
            for (int nn = 0; nn < 4; ++nn) {
                short8 f;
                #pragma unroll
                for (int j = 0; j < 8; ++j) {
                    const int k = kk * 32 + q * 8 + j;
                    f[j] = (short)f2bf(w2[k * 64 + nn * 16 + c]);
                }
                *(short8*)&W2f[kk][nn][lane * 8] = f;
            }
    }
    float b1v[4], b2v[4];
    #pragma unroll
    for (int nn = 0; nn < 4; ++nn) {
        b1v[nn] = b1[nn * 16 + c];
        b2v[nn] = b2[nn * 16 + c];
    }
    // zero pad region (cols 80..96) once — never overwritten
    if (q == 1) {
        const short8 z8 = {0, 0, 0, 0, 0, 0, 0, 0};
        *(short8*)&A1[wid][c * S1 + 80] = z8;
        *(short8*)&A1[wid][c * S1 + 88] = z8;
    }
    __syncthreads();

    const floatx4 zero = {0.f, 0.f, 0.f, 0.f};
    const int ntile = NE / 16;  // 50000
    const int stride = gridDim.x * 4;
    int t = blockIdx.x * 4 + wid;   // < 4096 << ntile always

    // ---- prologue: idx for tile t, idx for t+stride, data for t ----
    int sB, dB, iB;                  // idx regs for NEXT tile
    float4 xv0, xv1, xv2, xv3, ev;   // gathered data for CURRENT tile
    int dcur;
    {
        const int sA = srcs[t * 16 + c];
        dcur = dsts[t * 16 + c];
        const int iA = eidx[t * 16 + r4];
        int tb = t + stride; if (tb >= ntile) tb = ntile - 1;
        sB = srcs[tb * 16 + c];
        dB = dsts[tb * 16 + c];
        iB = eidx[tb * 16 + r4];
        const float4* xp = (const float4*)(x + (size_t)sA * 64 + q * 16);
        xv0 = xp[0]; xv1 = xp[1]; xv2 = xp[2]; xv3 = xp[3];
        ev = *(const float4*)(ef + (size_t)iA * 16 + p4 * 4);
    }

    for (; t < ntile; t += stride) {
        // ---- stage current tile into LDS ----
        u16* arow = &A1[wid][c * S1 + q * 16];
        *(short8*)arow       = pack8(xv0, xv1);
        *(short8*)(arow + 8) = pack8(xv2, xv3);
        {
            short4v e4;
            e4[0] = (short)f2bf(ev.x); e4[1] = (short)f2bf(ev.y);
            e4[2] = (short)f2bf(ev.z); e4[3] = (short)f2bf(ev.w);
            *(short4v*)&A1[wid][r4 * S1 + 64 + p4 * 4] = e4;
        }
        if (q == 0) Ds[wid][c] = dcur;
        LDS_FENCE();

        // A frags: A[m=c][k=32*kk+q*8+j]
        short8 a1k[3];
        #pragma unroll
        for (int kk = 0; kk < 3; ++kk)
            a1k[kk] = *(const short8*)&A1[wid][c * S1 + kk * 32 + q * 8];

        // ---- issue prefetch: data for t+stride (idx already resident) ----
        {
            const float4* xpn = (const float4*)(x + (size_t)sB * 64 + q * 16);
            xv0 = xpn[0]; xv1 = xpn[1]; xv2 = xpn[2]; xv3 = xpn[3];
            ev = *(const float4*)(ef + (size_t)iB * 16 + p4 * 4);
        }
        const int dnext = dB;
        // idx for t+2*stride
        {
            int tb = t + 2 * stride; if (tb >= ntile) tb = ntile - 1;
            sB = srcs[tb * 16 + c];
            dB = dsts[tb * 16 + c];
            iB = eidx[tb * 16 + r4];
        }

        // ---- GEMM1 + bias + relu -> Hs (bf16 row-major) ----
        #pragma unroll
        for (int nn = 0; nn < 4; ++nn) {
            floatx4 acc = MFMA16(a1k[0], w1f[0][nn], zero);
            acc = MFMA16(a1k[1], w1f[1][nn], acc);
            acc = MFMA16(a1k[2], w1f[2][nn], acc);
            #pragma unroll
            for (int r = 0; r < 4; ++r) {
                const float h = fmaxf(acc[r] + b1v[nn], 0.f);
                Hs[wid][(q * 4 + r) * S2 + nn * 16 + c] = f2bf(h);
            }
        }
        LDS_FENCE();

        short8 a2k[2];
        #pragma unroll
        for (int kk = 0; kk < 2; ++kk)
            a2k[kk] = *(const short8*)&Hs[wid][c * S2 + kk * 32 + q * 8];

        // ---- GEMM2 -> msg (bf16) overlaid into Hs ----
        #pragma unroll
        for (int nn = 0; nn < 4; ++nn) {
            const short8 wf0 = *(const short8*)&W2f[0][nn][lane * 8];
            const short8 wf1 = *(const short8*)&W2f[1][nn][lane * 8];
            floatx4 mg = MFMA16(a2k[0], wf0, zero);
            mg = MFMA16(a2k[1], wf1, mg);
            #pragma unroll
            for (int r = 0; r < 4; ++r)
                Hs[wid][(q * 4 + r) * S2 + nn * 16 + c] = f2bf(mg[r] + b2v[nn]);
        }
        LDS_FENCE();

        // ---- segmented reduction over sorted dst (lane = column) ----
        int dc = Ds[wid][0];
        float acc = bf2f(Hs[wid][lane]);
        #pragma unroll
        for (int row = 1; row < 16; ++row) {
            const int d = Ds[wid][row];
            const float v = bf2f(Hs[wid][row * S2 + lane]);
            if (d == dc) {
                acc += v;
            } else {
                atomicAdd(&agg[(size_t)dc * 64 + lane], acc);
                dc = d;
                acc = v;
            }
        }
        atomicAdd(&agg[(size_t)dc * 64 + lane], acc);

        dcur = dnext;
    }
}

// ---------------------------------------------------------------------------
// Node kernel: per 16-node tile (one wave):
//   cat[16x128] = [bf16(x) | bf16(agg/(cnt+1e-8))], cnt = hist (int)
//   upd = relu(cat @ W3 + b3); y = upd + x; LayerNorm(y)*gamma+beta -> fp32 out
// ---------------------------------------------------------------------------
__global__ __launch_bounds__(256) void node_kernel(
    const float* __restrict__ x, const float* __restrict__ w3,
    const float* __restrict__ b3, const float* __restrict__ g,
    const float* __restrict__ bb, const float* __restrict__ agg,
    const int* __restrict__ hist, float* __restrict__ out)
{
    constexpr int S3 = 136;  // 128 + 8 pad
    __shared__ u16 Cs[4][16 * S3];

    const int wid  = threadIdx.x >> 6;
    const int lane = threadIdx.x & 63;
    const int q    = lane >> 4;
    const int c    = lane & 15;

    short8 w3f[4][4];
    #pragma unroll
    for (int kk = 0; kk < 4; ++kk)
        #pragma unroll
        for (int nn = 0; nn < 4; ++nn)
            #pragma unroll
            for (int j = 0; j < 8; ++j) {
                const int k = kk * 32 + q * 8 + j;
                w3f[kk][nn][j] = (short)f2bf(w3[k * 64 + nn * 16 + c]);
            }
    float b3v[4], gv[4], bv[4];
    #pragma unroll
    for (int nn = 0; nn < 4; ++nn) {
        b3v[nn] = b3[nn * 16 + c];
        gv[nn]  = g[nn * 16 + c];
        bv[nn]  = bb[nn * 16 + c];
    }

    const floatx4 zero = {0.f, 0.f, 0.f, 0.f};
    const int ntile = NNODES / 16;  // 3125

    for (int t = blockIdx.x * 4 + wid; t < ntile; t += gridDim.x * 4) {
        const int n0 = t * 16;
        const int node = n0 + c;
        u16* crow = &Cs[wid][c * S3];

        if (q < 2) {
            const float* xp = x + (size_t)node * 64 + q * 32;
            #pragma unroll
            for (int gi = 0; gi < 4; ++gi)
                *(short8*)&crow[q * 32 + gi * 8] = ld8_bf(xp + gi * 8);
        } else {
            const int p = q - 2;
            const float inv = 1.0f / ((float)hist[node] + 1e-8f);
            const float* ap = agg + (size_t)node * 64 + p * 32;
            #pragma unroll
            for (int gi = 0; gi < 4; ++gi) {
                const float4 v0 = *(const float4*)(ap + gi * 8);
                const float4 v1 = *(const float4*)(ap + gi * 8 + 4);
                short8 o;
                o[0] = (short)f2bf(v0.x * inv);
                o[1] = (short)f2bf(v0.y * inv);
                o[2] = (short)f2bf(v0.z * inv);
                o[3] = (short)f2bf(v0.w * inv);
                o[4] = (short)f2bf(v1.x * inv);
                o[5] = (short)f2bf(v1.y * inv);
                o[6] = (short)f2bf(v1.z * inv);
                o[7] = (short)f2bf(v1.w * inv);
                *(short8*)&crow[64 + p * 32 + gi * 8] = o;
            }
        }
        LDS_FENCE();

        short8 af[4];
        #pragma unroll
        for (int kk = 0; kk < 4; ++kk)
            af[kk] = *(const short8*)&Cs[wid][c * S3 + kk * 32 + q * 8];

        float y[4][4];
        float s[4]  = {0.f, 0.f, 0.f, 0.f};
        float ss[4] = {0.f, 0.f, 0.f, 0.f};
        #pragma unroll
        for (int nn = 0; nn < 4; ++nn) {
            floatx4 acc = MFMA16(af[0], w3f[0][nn], zero);
            acc = MFMA16(af[1], w3f[1][nn], acc);
            acc = MFMA16(af[2], w3f[2][nn], acc);
            acc = MFMA16(af[3], w3f[3][nn], acc);
            #pragma unroll
            for (int r = 0; r < 4; ++r) {
                const float upd = fmaxf(acc[r] + b3v[nn], 0.f);
                const float xv = bf2f(Cs[wid][(q * 4 + r) * S3 + nn * 16 + c]);
                const float yy = upd + xv;
                y[r][nn] = yy;
                s[r] += yy;
                ss[r] += yy * yy;
            }
        }

        #pragma unroll
        for (int r = 0; r < 4; ++r) {
            float sr = s[r], sq = ss[r];
            #pragma unroll
            for (int off = 1; off < 16; off <<= 1) {
                sr += __shfl_xor(sr, off);
                sq += __shfl_xor(sq, off);
            }
            const float mu  = sr * (1.0f / 64.0f);
            const float var = sq * (1.0f / 64.0f) - mu * mu;
            const float rs  = rsqrtf(var + 1e-5f);
            float* op = out + (size_t)(n0 + q * 4 + r) * 64 + c;
            #pragma unroll
            for (int nn = 0; nn < 4; ++nn)
                op[nn * 16] = (y[r][nn] - mu) * rs * gv[nn] + bv[nn];
        }
    }
}

extern "C" void kernel_launch(void* const* d_in, const int* in_sizes, int n_in,
                              void* d_out, int out_size, void* d_ws, size_t ws_size,
                              hipStream_t stream) {
    const float* x   = (const float*)d_in[0];
    const int*   ei  = (const int*)d_in[1];
    const float* ef  = (const float*)d_in[2];
    const float* w1  = (const float*)d_in[3];
    const float* b1  = (const float*)d_in[4];
    const float* w2  = (const float*)d_in[5];
    const float* b2  = (const float*)d_in[6];
    const float* w3  = (const float*)d_in[7];
    const float* b3  = (const float*)d_in[8];
    const float* g   = (const float*)d_in[9];
    const float* bb  = (const float*)d_in[10];

    // ws layout (4B units):
    // agg[3.2M] | hist[50k] | cursor[50k] | bsum[256] | bsumx[256]
    // | srcs[800k] | dsts[800k] | eidx[800k]
    float* agg   = (float*)d_ws;
    int* hist    = (int*)d_ws + 3200000;
    int* cursor  = hist + NNODES;
    int* bsum    = cursor + NNODES;
    int* bsumx   = bsum + 256;
    int* srcs    = bsumx + 256;
    int* dsts    = srcs + NE;
    int* eidx    = dsts + NE;

    // zero agg + hist in one contiguous memset
    hipMemsetAsync(d_ws, 0, (size_t)(3200000 + NNODES) * sizeof(float), stream);
    hist_kernel<<<(NE + 255) / 256, 256, 0, stream>>>(ei, hist);
    scan1_kernel<<<NBLK, 256, 0, stream>>>(hist, cursor, bsum);
    scan2_kernel<<<1, 256, 0, stream>>>(bsum, bsumx);
    scan3_kernel<<<NBLK, 256, 0, stream>>>(cursor, bsumx);
    scatter_kernel<<<(NE + 255) / 256, 256, 0, stream>>>(ei, cursor, srcs, dsts, eidx);
    edge_kernel<<<1024, 256, 0, stream>>>(x, ef, w1, b1, w2, b2, srcs, dsts, eidx, agg);
    node_kernel<<<392, 256, 0, stream>>>(x, w3, b3, g, bb, agg, hist, (float*)d_out);
}

// Round 7
// 287.509 us; speedup vs baseline: 1.4461x; 1.0395x over previous
//
#include <hip/hip_runtime.h>

typedef unsigned short u16;
typedef unsigned int u32;
typedef short short8 __attribute__((ext_vector_type(8)));
typedef short short4v __attribute__((ext_vector_type(4)));
typedef float floatx4 __attribute__((ext_vector_type(4)));

#define NE 800000
#define NNODES 50000
#define NBLK 196  // ceil(50000/256)

#define LDS_FENCE() __asm__ volatile("s_waitcnt lgkmcnt(0)" ::: "memory")

__device__ __forceinline__ u16 f2bf(float f) {
    union { float f; unsigned int i; } v; v.f = f;
    return (u16)((v.i + 0x7fffu + ((v.i >> 16) & 1u)) >> 16);
}
__device__ __forceinline__ float bf2f(u16 u) {
    union { unsigned int i; float f; } v; v.i = ((unsigned int)u) << 16; return v.f;
}
__device__ __forceinline__ short8 pack8(const float4 a, const float4 b) {
    short8 o;
    o[0] = (short)f2bf(a.x); o[1] = (short)f2bf(a.y);
    o[2] = (short)f2bf(a.z); o[3] = (short)f2bf(a.w);
    o[4] = (short)f2bf(b.x); o[5] = (short)f2bf(b.y);
    o[6] = (short)f2bf(b.z); o[7] = (short)f2bf(b.w);
    return o;
}
__device__ __forceinline__ short8 ld8_bf(const float* __restrict__ p) {
    return pack8(*(const float4*)p, *(const float4*)(p + 4));
}

#define MFMA16(a, b, c) __builtin_amdgcn_mfma_f32_16x16x32_bf16(a, b, c, 0, 0, 0)

// ---------------------------------------------------------------------------
// prep: dst histogram (atomics) + x -> bf16 conversion, merged
// ---------------------------------------------------------------------------
__global__ __launch_bounds__(256) void prep_kernel(
    const float* __restrict__ x, const int* __restrict__ ei,
    int* __restrict__ hist, u16* __restrict__ xbf)
{
    const int id = blockIdx.x * 256 + threadIdx.x;
    if (id < NE) atomicAdd(&hist[ei[NE + id]], 1);
    if (id < NNODES * 8) {  // 400000 threads x 8 elems = 3.2M
        *(short8*)&xbf[(size_t)id * 8] = ld8_bf(x + (size_t)id * 8);
    }
}

// per-block exclusive scan (shuffle), local excl + block total
__global__ __launch_bounds__(256) void scan1_kernel(
    const int* __restrict__ hist, int* __restrict__ cursor, int* __restrict__ bsum)
{
    const int i = blockIdx.x * 256 + threadIdx.x;
    const int lane = threadIdx.x & 63;
    const int w = threadIdx.x >> 6;
    const int v = (i < NNODES) ? hist[i] : 0;
    int inc = v;
    #pragma unroll
    for (int o = 1; o < 64; o <<= 1) {
        const int tt = __shfl_up(inc, o);
        if (lane >= o) inc += tt;
    }
    __shared__ int ws[4];
    if (lane == 63) ws[w] = inc;
    __syncthreads();
    int add = 0;
    for (int j = 0; j < w; ++j) add += ws[j];
    const int excl = inc - v + add;
    if (i < NNODES) cursor[i] = excl;
    if (threadIdx.x == 255) bsum[blockIdx.x] = excl + v;
}

// scan the block totals (<=256) in one block
__global__ __launch_bounds__(256) void scan2_kernel(
    const int* __restrict__ bsum, int* __restrict__ bsumx)
{
    const int tid = threadIdx.x;
    const int lane = tid & 63;
    const int w = tid >> 6;
    const int v = (tid < NBLK) ? bsum[tid] : 0;
    int inc = v;
    #pragma unroll
    for (int o = 1; o < 64; o <<= 1) {
        const int tt = __shfl_up(inc, o);
        if (lane >= o) inc += tt;
    }
    __shared__ int ws[4];
    if (lane == 63) ws[w] = inc;
    __syncthreads();
    int add = 0;
    for (int j = 0; j < w; ++j) add += ws[j];
    bsumx[tid] = inc - v + add;
}

// scatter: ONE 8-byte packed record per edge: (.y = src<<16|dst, .x = e)
__global__ __launch_bounds__(256) void scatter_kernel(
    const int* __restrict__ ei, int* __restrict__ cursor,
    const int* __restrict__ bsumx, uint2* __restrict__ sde)
{
    const int e = blockIdx.x * 256 + threadIdx.x;
    if (e < NE) {
        const int dst = ei[NE + e];
        const int p = atomicAdd(&cursor[dst], 1) + bsumx[dst >> 8];
        uint2 v;
        v.x = (u32)e;
        v.y = ((u32)ei[e] << 16) | (u32)dst;
        sde[p] = v;
    }
}

// ---------------------------------------------------------------------------
// Edge kernel, software-pipelined, dst-sorted via sde records:
//   A1[16x96] = [xbf[src] copy | bf16(edge_feat) | zero pad]
//   h   = relu(A1 @ W1 + b1)   (MFMA K=96, W1 zero-padded k>=80)
//   msg = h @ W2 + b2          (W2 frags from LDS; msg bf16 overlaid in Hs)
//   segmented per-wave reduction over sorted dst -> ~2 atomics/lane/tile
// ---------------------------------------------------------------------------
__global__ __launch_bounds__(256) void edge_kernel(
    const u16* __restrict__ xbf, const float* __restrict__ ef,
    const float* __restrict__ w1, const float* __restrict__ b1,
    const float* __restrict__ w2, const float* __restrict__ b2,
    const uint2* __restrict__ sde, float* __restrict__ agg)
{
    constexpr int S1 = 104;  // A1 row stride (bf16): pad 96->104
    constexpr int S2 = 72;   // h/msg row stride: pad 64->72
    __shared__ u16 A1[4][16 * S1];
    __shared__ u16 Hs[4][16 * S2];
    __shared__ int Ds[4][16];
    __shared__ u16 W2f[2][4][64 * 8];  // per-lane W2 B-frags (8 KB)

    const int wid  = threadIdx.x >> 6;
    const int lane = threadIdx.x & 63;
    const int q    = lane >> 4;   // quad
    const int c    = lane & 15;   // col within quad
    const int r4   = lane >> 2;   // ef row handled by this lane
    const int p4   = lane & 3;    // ef float4 part

    // W1 B-frags in registers. B[k][n]: n=16*nn+c, k=32*kk+q*8+j
    short8 w1f[3][4];
    #pragma unroll
    for (int kk = 0; kk < 3; ++kk)
        #pragma unroll
        for (int nn = 0; nn < 4; ++nn)
            #pragma unroll
            for (int j = 0; j < 8; ++j) {
                const int k = kk * 32 + q * 8 + j;
                w1f[kk][nn][j] = (k < 80) ? (short)f2bf(w1[k * 64 + nn * 16 + c]) : (short)0;
            }
    // W2 B-frags into LDS once
    if (wid == 0) {
        #pragma unroll
        for (int kk = 0; kk < 2; ++kk)
            #pragma unroll
            for (int nn = 0; nn < 4; ++nn) {
                short8 f;
                #pragma unroll
                for (int j = 0; j < 8; ++j) {
                    const int k = kk * 32 + q * 8 + j;
                    f[j] = (short)f2bf(w2[k * 64 + nn * 16 + c]);
                }
                *(short8*)&W2f[kk][nn][lane * 8] = f;
            }
    }
    float b1v[4], b2v[4];
    #pragma unroll
    for (int nn = 0; nn < 4; ++nn) {
        b1v[nn] = b1[nn * 16 + c];
        b2v[nn] = b2[nn * 16 + c];
    }
    // zero pad region (cols 80..96) once — never overwritten
    if (q == 1) {
        const short8 z8 = {0, 0, 0, 0, 0, 0, 0, 0};
        *(short8*)&A1[wid][c * S1 + 80] = z8;
        *(short8*)&A1[wid][c * S1 + 88] = z8;
    }
    __syncthreads();

    const floatx4 zero = {0.f, 0.f, 0.f, 0.f};
    const int ntile = NE / 16;  // 50000
    const int stride = gridDim.x * 4;
    int t = blockIdx.x * 4 + wid;

    // ---- prologue: idx for t and t+stride, data for t ----
    uint2 sdB; u32 eB;               // idx regs for NEXT tile
    short8 xa, xb; float4 ev;        // gathered data for CURRENT tile
    int dcur;
    {
        const uint2 sdA = sde[t * 16 + c];
        const u32  eA  = sde[t * 16 + r4].x;
        dcur = (int)(sdA.y & 0xffffu);
        const int sA = (int)(sdA.y >> 16);
        int tb = t + stride; if (tb >= ntile) tb = ntile - 1;
        sdB = sde[tb * 16 + c];
        eB  = sde[tb * 16 + r4].x;
        const u16* xp = xbf + (size_t)sA * 64 + q * 16;
        xa = *(const short8*)xp;
        xb = *(const short8*)(xp + 8);
        ev = *(const float4*)(ef + (size_t)eA * 16 + p4 * 4);
    }

    for (; t < ntile; t += stride) {
        // ---- stage current tile into LDS (pure copies for x) ----
        u16* arow = &A1[wid][c * S1 + q * 16];
        *(short8*)arow       = xa;
        *(short8*)(arow + 8) = xb;
        {
            short4v e4;
            e4[0] = (short)f2bf(ev.x); e4[1] = (short)f2bf(ev.y);
            e4[2] = (short)f2bf(ev.z); e4[3] = (short)f2bf(ev.w);
            *(short4v*)&A1[wid][r4 * S1 + 64 + p4 * 4] = e4;
        }
        if (q == 0) Ds[wid][c] = dcur;
        LDS_FENCE();

        // A frags: A[m=c][k=32*kk+q*8+j]
        short8 a1k[3];
        #pragma unroll
        for (int kk = 0; kk < 3; ++kk)
            a1k[kk] = *(const short8*)&A1[wid][c * S1 + kk * 32 + q * 8];

        // ---- prefetch data for t+stride (idx already resident) ----
        const int dnext = (int)(sdB.y & 0xffffu);
        {
            const int sN = (int)(sdB.y >> 16);
            const u16* xp = xbf + (size_t)sN * 64 + q * 16;
            xa = *(const short8*)xp;
            xb = *(const short8*)(xp + 8);
            ev = *(const float4*)(ef + (size_t)eB * 16 + p4 * 4);
        }
        // idx for t+2*stride
        {
            int tb = t + 2 * stride; if (tb >= ntile) tb = ntile - 1;
            sdB = sde[tb * 16 + c];
            eB  = sde[tb * 16 + r4].x;
        }

        // ---- GEMM1 + bias + relu -> Hs (bf16 row-major) ----
        #pragma unroll
        for (int nn = 0; nn < 4; ++nn) {
            floatx4 acc = MFMA16(a1k[0], w1f[0][nn], zero);
            acc = MFMA16(a1k[1], w1f[1][nn], acc);
            acc = MFMA16(a1k[2], w1f[2][nn], acc);
            #pragma unroll
            for (int r = 0; r < 4; ++r) {
                const float h = fmaxf(acc[r] + b1v[nn], 0.f);
                Hs[wid][(q * 4 + r) * S2 + nn * 16 + c] = f2bf(h);
            }
        }
        LDS_FENCE();

        short8 a2k[2];
        #pragma unroll
        for (int kk = 0; kk < 2; ++kk)
            a2k[kk] = *(const short8*)&Hs[wid][c * S2 + kk * 32 + q * 8];

        // ---- GEMM2 -> msg (bf16) overlaid into Hs ----
        #pragma unroll
        for (int nn = 0; nn < 4; ++nn) {
            const short8 wf0 = *(const short8*)&W2f[0][nn][lane * 8];
            const short8 wf1 = *(const short8*)&W2f[1][nn][lane * 8];
            floatx4 mg = MFMA16(a2k[0], wf0, zero);
            mg = MFMA16(a2k[1], wf1, mg);
            #pragma unroll
            for (int r = 0; r < 4; ++r)
                Hs[wid][(q * 4 + r) * S2 + nn * 16 + c] = f2bf(mg[r] + b2v[nn]);
        }
        LDS_FENCE();

        // ---- segmented reduction over sorted dst (lane = column) ----
        int dc = Ds[wid][0];
        float acc = bf2f(Hs[wid][lane]);
        #pragma unroll
        for (int row = 1; row < 16; ++row) {
            const int d = Ds[wid][row];
            const float v = bf2f(Hs[wid][row * S2 + lane]);
            if (d == dc) {
                acc += v;
            } else {
                atomicAdd(&agg[(size_t)dc * 64 + lane], acc);
                dc = d;
                acc = v;
            }
        }
        atomicAdd(&agg[(size_t)dc * 64 + lane], acc);

        dcur = dnext;
    }
}

// ---------------------------------------------------------------------------
// Node kernel: per 16-node tile (one wave):
//   cat[16x128] = [xbf copy | bf16(agg/(cnt+1e-8))], cnt = hist
//   upd = relu(cat @ W3 + b3); y = upd + x; LayerNorm(y)*gamma+beta -> fp32 out
// ---------------------------------------------------------------------------
__global__ __launch_bounds__(256) void node_kernel(
    const u16* __restrict__ xbf, const float* __restrict__ w3,
    const float* __restrict__ b3, const float* __restrict__ g,
    const float* __restrict__ bb, const float* __restrict__ agg,
    const int* __restrict__ hist, float* __restrict__ out)
{
    constexpr int S3 = 136;  // 128 + 8 pad
    __shared__ u16 Cs[4][16 * S3];

    const int wid  = threadIdx.x >> 6;
    const int lane = threadIdx.x & 63;
    const int q    = lane >> 4;
    const int c    = lane & 15;

    short8 w3f[4][4];
    #pragma unroll
    for (int kk = 0; kk < 4; ++kk)
        #pragma unroll
        for (int nn = 0; nn < 4; ++nn)
            #pragma unroll
            for (int j = 0; j < 8; ++j) {
                const int k = kk * 32 + q * 8 + j;
                w3f[kk][nn][j] = (short)f2bf(w3[k * 64 + nn * 16 + c]);
            }
    float b3v[4], gv[4], bv[4];
    #pragma unroll
    for (int nn = 0; nn < 4; ++nn) {
        b3v[nn] = b3[nn * 16 + c];
        gv[nn]  = g[nn * 16 + c];
        bv[nn]  = bb[nn * 16 + c];
    }

    const floatx4 zero = {0.f, 0.f, 0.f, 0.f};
    const int ntile = NNODES / 16;  // 3125

    for (int t = blockIdx.x * 4 + wid; t < ntile; t += gridDim.x * 4) {
        const int n0 = t * 16;
        const int node = n0 + c;
        u16* crow = &Cs[wid][c * S3];

        if (q < 2) {
            const u16* xp = xbf + (size_t)node * 64 + q * 32;
            *(short8*)&crow[q * 32]      = *(const short8*)xp;
            *(short8*)&crow[q * 32 + 8]  = *(const short8*)(xp + 8);
            *(short8*)&crow[q * 32 + 16] = *(const short8*)(xp + 16);
            *(short8*)&crow[q * 32 + 24] = *(const short8*)(xp + 24);
        } else {
            const int p = q - 2;
            const float inv = 1.0f / ((float)hist[node] + 1e-8f);
            const float* ap = agg + (size_t)node * 64 + p * 32;
            #pragma unroll
            for (int gi = 0; gi < 4; ++gi) {
                const float4 v0 = *(const float4*)(ap + gi * 8);
                const float4 v1 = *(const float4*)(ap + gi * 8 + 4);
                short8 o;
                o[0] = (short)f2bf(v0.x * inv);
                o[1] = (short)f2bf(v0.y * inv);
                o[2] = (short)f2bf(v0.z * inv);
                o[3] = (short)f2bf(v0.w * inv);
                o[4] = (short)f2bf(v1.x * inv);
                o[5] = (short)f2bf(v1.y * inv);
                o[6] = (short)f2bf(v1.z * inv);
                o[7] = (short)f2bf(v1.w * inv);
                *(short8*)&crow[64 + p * 32 + gi * 8] = o;
            }
        }
        LDS_FENCE();

        short8 af[4];
        #pragma unroll
        for (int kk = 0; kk < 4; ++kk)
            af[kk] = *(const short8*)&Cs[wid][c * S3 + kk * 32 + q * 8];

        float y[4][4];
        float s[4]  = {0.f, 0.f, 0.f, 0.f};
        float ss[4] = {0.f, 0.f, 0.f, 0.f};
        #pragma unroll
        for (int nn = 0; nn < 4; ++nn) {
            floatx4 acc = MFMA16(af[0], w3f[0][nn], zero);
            acc = MFMA16(af[1], w3f[1][nn], acc);
            acc = MFMA16(af[2], w3f[2][nn], acc);
            acc = MFMA16(af[3], w3f[3][nn], acc);
            #pragma unroll
            for (int r = 0; r < 4; ++r) {
                const float upd = fmaxf(acc[r] + b3v[nn], 0.f);
                const float xv = bf2f(Cs[wid][(q * 4 + r) * S3 + nn * 16 + c]);
                const float yy = upd + xv;
                y[r][nn] = yy;
                s[r] += yy;
                ss[r] += yy * yy;
            }
        }

        #pragma unroll
        for (int r = 0; r < 4; ++r) {
            float sr = s[r], sq = ss[r];
            #pragma unroll
            for (int off = 1; off < 16; off <<= 1) {
                sr += __shfl_xor(sr, off);
                sq += __shfl_xor(sq, off);
            }
            const float mu  = sr * (1.0f / 64.0f);
            const float var = sq * (1.0f / 64.0f) - mu * mu;
            const float rs  = rsqrtf(var + 1e-5f);
            float* op = out + (size_t)(n0 + q * 4 + r) * 64 + c;
            #pragma unroll
            for (int nn = 0; nn < 4; ++nn)
                op[nn * 16] = (y[r][nn] - mu) * rs * gv[nn] + bv[nn];
        }
    }
}

extern "C" void kernel_launch(void* const* d_in, const int* in_sizes, int n_in,
                              void* d_out, int out_size, void* d_ws, size_t ws_size,
                              hipStream_t stream) {
    const float* x   = (const float*)d_in[0];
    const int*   ei  = (const int*)d_in[1];
    const float* ef  = (const float*)d_in[2];
    const float* w1  = (const float*)d_in[3];
    const float* b1  = (const float*)d_in[4];
    const float* w2  = (const float*)d_in[5];
    const float* b2  = (const float*)d_in[6];
    const float* w3  = (const float*)d_in[7];
    const float* b3  = (const float*)d_in[8];
    const float* g   = (const float*)d_in[9];
    const float* bb  = (const float*)d_in[10];

    // ws layout (u32 units):
    // agg[3.2M] | hist[50k] | cursor[50k] | bsum[256] | bsumx[256]
    // | xbf (3.2M u16 = 1.6M u32) | sde (800k uint2 = 1.6M u32)
    float* agg   = (float*)d_ws;
    int* hist    = (int*)d_ws + 3200000;
    int* cursor  = hist + NNODES;
    int* bsum    = cursor + NNODES;
    int* bsumx   = bsum + 256;
    u16* xbf     = (u16*)(bsumx + 256);
    uint2* sde   = (uint2*)((int*)d_ws + 4900512);

    // zero agg + hist in one contiguous memset
    hipMemsetAsync(d_ws, 0, (size_t)(3200000 + NNODES) * sizeof(float), stream);
    prep_kernel<<<3125, 256, 0, stream>>>(x, ei, hist, xbf);
    scan1_kernel<<<NBLK, 256, 0, stream>>>(hist, cursor, bsum);
    scan2_kernel<<<1, 256, 0, stream>>>(bsum, bsumx);
    scatter_kernel<<<3125, 256, 0, stream>>>(ei, cursor, bsumx, sde);
    edge_kernel<<<2048, 256, 0, stream>>>(xbf, ef, w1, b1, w2, b2, sde, agg);
    node_kernel<<<782, 256, 0, stream>>>(xbf, w3, b3, g, bb, agg, hist, (float*)d_out);
}